// Round 1
// baseline (1211.434 us; speedup 1.0000x reference)
//
#include <hip/hip_runtime.h>
#include <hip/hip_bf16.h>
#include <math.h>

// Problem constants (match reference)
#define Bb 2
#define Hh 28
#define Ww 28
#define Ll 784          // H*W
#define DMm 384
#define DINn 768        // DM*EXPAND
#define DSs 16
#define DTRr 24
#define Ee 56           // DTR + 2*DS
#define Kk 4
#define BL 1568         // B*L

// scan-position mapping: spatial index p for scan index l, direction k
__device__ __forceinline__ int spos(int k, int l) {
    if (k == 0) return l;
    if (k == 1) return (l % 28) * 28 + l / 28;
    if (k == 3) l = 783 - l;
    int j = l % 7;
    int i = (l / 7) % 7;
    int wg = (l / 49) % 4;
    int hg = l / 196;
    return (hg * 7 + i) * 28 + wg * 7 + j;
}

// ---------------- Generic tiled GEMM: C[m,n] = epi( sum_k A[m,k]*B[n,k] ) ----------------
#define BM 64
#define BN 64
#define BKk 16

__global__ __launch_bounds__(256) void gemm_abt(
    const float* __restrict__ A, const float* __restrict__ B, float* __restrict__ C,
    int M, int N, int K, int lda, int ldb, int ldc,
    long sA, long sB, long sC,
    const float* __restrict__ bias, long sBias, int epi)
{
    int z = blockIdx.z;
    A += (long)z * sA; B += (long)z * sB; C += (long)z * sC;
    if (bias) bias += (long)z * sBias;
    int n0 = blockIdx.x * BN;
    int m0 = blockIdx.y * BM;
    __shared__ float As[BKk][BM];
    __shared__ float Bs[BKk][BN];
    int t = threadIdx.x;
    int tx = t & 15, ty = t >> 4;
    float acc[4][4] = {};
    for (int k0 = 0; k0 < K; k0 += BKk) {
#pragma unroll
        for (int i = 0; i < 4; ++i) {
            int r = (t >> 4) + 16 * i;
            int k = t & 15;
            float va = 0.f, vb = 0.f;
            if (m0 + r < M && k0 + k < K) va = A[(long)(m0 + r) * lda + k0 + k];
            if (n0 + r < N && k0 + k < K) vb = B[(long)(n0 + r) * ldb + k0 + k];
            As[k][r] = va;
            Bs[k][r] = vb;
        }
        __syncthreads();
#pragma unroll
        for (int kk = 0; kk < BKk; ++kk) {
            float a[4], b[4];
#pragma unroll
            for (int i = 0; i < 4; ++i) a[i] = As[kk][ty * 4 + i];
#pragma unroll
            for (int j = 0; j < 4; ++j) b[j] = Bs[kk][tx * 4 + j];
#pragma unroll
            for (int i = 0; i < 4; ++i)
#pragma unroll
                for (int j = 0; j < 4; ++j)
                    acc[i][j] += a[i] * b[j];
        }
        __syncthreads();
    }
#pragma unroll
    for (int i = 0; i < 4; ++i) {
        int m = m0 + ty * 4 + i;
        if (m >= M) continue;
#pragma unroll
        for (int j = 0; j < 4; ++j) {
            int n = n0 + tx * 4 + j;
            if (n >= N) continue;
            float v = acc[i][j];
            if (epi == 1) {
                v += bias[n];
                v = fmaxf(v, 0.f) + log1pf(expf(-fabsf(v)));  // softplus, stable
            }
            C[(long)m * ldc + n] = v;
        }
    }
}

// ---------------- depthwise causal conv (k=4) + SiLU, with scan gather ----------------
// conv[k][b][l][d] layout, d contiguous
__global__ __launch_bounds__(256) void conv_kernel(
    const float* __restrict__ xz, const float* __restrict__ conv_w,
    const float* __restrict__ conv_b, float* __restrict__ conv)
{
    int l = blockIdx.x;
    int kb = blockIdx.y;       // k*2 + b
    int k = kb >> 1, b = kb & 1;
    // gather positions for l-3..l
    int p[4];
#pragma unroll
    for (int j = 0; j < 4; ++j) {
        int lp = l - 3 + j;
        p[j] = (lp >= 0) ? spos(k, lp) : -1;
    }
    for (int d = threadIdx.x; d < DINn; d += 256) {
        float acc = conv_b[k * DINn + d];
        const float* w = conv_w + (long)(k * DINn + d) * 4;
#pragma unroll
        for (int j = 0; j < 4; ++j) {
            if (p[j] >= 0)
                acc += w[j] * xz[((long)b * Ll + p[j]) * (2 * DINn) + d];
        }
        acc = acc / (1.f + expf(-acc));   // SiLU
        conv[((long)kb * Ll + l) * DINn + d] = acc;
    }
}

// ---------------- selective scan: thread = (k,b,d,n) ----------------
__global__ __launch_bounds__(256) void scan_kernel(
    const float* __restrict__ delta, const float* __restrict__ conv,
    const float* __restrict__ xdbl, const float* __restrict__ A_log,
    const float* __restrict__ Dp, const float* __restrict__ xz,
    float* __restrict__ outy)
{
    int t = blockIdx.x * 256 + threadIdx.x;     // 0..98303
    int n = t & 15;
    int rest = t >> 4;                          // (k*2+b)*768 + d
    int d = rest % DINn;
    int kb = rest / DINn;
    int k = kb >> 1, b = kb & 1;

    float An = -expf(A_log[((long)k * DINn + d) * DSs + n]);
    float Dv = Dp[k * DINn + d];
    const float* dl = delta + (long)kb * Ll * DINn + d;   // stride DINn per l
    const float* cl = conv + (long)kb * Ll * DINn + d;
    const float* xd = xdbl + (long)kb * Ll * Ee;          // stride Ee per l
    float h = 0.f;
    for (int l = 0; l < Ll; ++l) {
        float de = dl[(long)l * DINn];
        float cv = cl[(long)l * DINn];
        float Bv = xd[(long)l * Ee + DTRr + n];
        float Cv = xd[(long)l * Ee + DTRr + DSs + n];
        float dA = expf(de * An);
        h = dA * h + de * cv * Bv;
        float contrib = h * Cv;
        contrib += __shfl_xor(contrib, 1);
        contrib += __shfl_xor(contrib, 2);
        contrib += __shfl_xor(contrib, 4);
        contrib += __shfl_xor(contrib, 8);
        if (n == 0) {
            float y = contrib + Dv * cv;
            int p = spos(k, l);
            float zv = xz[((long)b * Ll + p) * (2 * DINn) + DINn + d];
            y *= zv / (1.f + expf(-zv));           // * z*sigmoid(z)
            outy[((long)kb * Ll + p) * DINn + d] = y;   // scatter = rev_k
        }
    }
}

// ---------------- LayerNorm stats per (kb, l) ----------------
__global__ __launch_bounds__(256) void ln_stats_kernel(
    const float* __restrict__ outy, float* __restrict__ mu, float* __restrict__ rstd)
{
    int l = blockIdx.x, kb = blockIdx.y;
    const float* row = outy + ((long)kb * Ll + l) * DINn;
    float s = 0.f, ss = 0.f;
    for (int d = threadIdx.x; d < DINn; d += 256) {
        float v = row[d];
        s += v; ss += v * v;
    }
#pragma unroll
    for (int o = 32; o > 0; o >>= 1) {
        s += __shfl_down(s, o);
        ss += __shfl_down(ss, o);
    }
    __shared__ float sh[8];
    int wid = threadIdx.x >> 6;
    if ((threadIdx.x & 63) == 0) { sh[wid] = s; sh[wid + 4] = ss; }
    __syncthreads();
    if (threadIdx.x == 0) {
        s = sh[0] + sh[1] + sh[2] + sh[3];
        ss = sh[4] + sh[5] + sh[6] + sh[7];
        float m = s / DINn;
        float var = ss / DINn - m * m;
        mu[(long)kb * Ll + l] = m;
        rstd[(long)kb * Ll + l] = rsqrtf(var + 1e-5f);
    }
}

// ---------------- g[kb][d] = ln_g[d]*mean_l((x-mu)*rstd) + ln_b[d] ----------------
__global__ __launch_bounds__(768) void g_kernel(
    const float* __restrict__ outy, const float* __restrict__ mu,
    const float* __restrict__ rstd, const float* __restrict__ ln_g,
    const float* __restrict__ ln_b, float* __restrict__ gbuf)
{
    int kb = blockIdx.x;
    int d = threadIdx.x;
    float acc = 0.f;
    for (int l = 0; l < Ll; ++l) {
        float v = outy[((long)kb * Ll + l) * DINn + d];
        acc += (v - mu[(long)kb * Ll + l]) * rstd[(long)kb * Ll + l];
    }
    gbuf[kb * DINn + d] = ln_g[d] * (acc / (float)Ll) + ln_b[d];
}

// ---------------- attn[kb][d] = sigmoid(cs(gelu(gr(g)))) ----------------
__global__ __launch_bounds__(256) void attn_kernel(
    const float* __restrict__ gbuf, const float* __restrict__ gr_w,
    const float* __restrict__ gr_b, const float* __restrict__ cs_w,
    const float* __restrict__ cs_b, float* __restrict__ attn)
{
    __shared__ float gs[DINn];
    __shared__ float hs[96];
    int kb = blockIdx.x;
    int t = threadIdx.x;
    for (int d = t; d < DINn; d += 256) gs[d] = gbuf[kb * DINn + d];
    __syncthreads();
    if (t < 96) {
        float a = gr_b[t];
        const float* wrow = gr_w + (long)t * DINn;
        for (int d = 0; d < DINn; ++d) a += wrow[d] * gs[d];
        hs[t] = 0.5f * a * (1.f + erff(a * 0.70710678118654752f));  // exact gelu
    }
    __syncthreads();
    for (int d = t; d < DINn; d += 256) {
        float a = cs_b[d];
        const float* wrow = cs_w + (long)d * 96;
        for (int e = 0; e < 96; ++e) a += wrow[e] * hs[e];
        attn[kb * DINn + d] = 1.f / (1.f + expf(-a));
    }
}

// ---------------- weighted sum over directions ----------------
__global__ __launch_bounds__(256) void wsum_kernel(
    const float* __restrict__ outy, const float* __restrict__ attn,
    float* __restrict__ sbuf)
{
    long idx = (long)blockIdx.x * 256 + threadIdx.x;   // over B*L*DIN
    if (idx >= (long)Bb * Ll * DINn) return;
    int d = idx % DINn;
    long bl = idx / DINn;          // b*L + p
    int b = (int)(bl / Ll);
    float acc = 0.f;
#pragma unroll
    for (int k = 0; k < Kk; ++k) {
        int kb = k * 2 + b;
        acc += outy[((long)kb * Ll + (bl % Ll)) * DINn + d] * attn[kb * DINn + d];
    }
    sbuf[idx] = acc;
}

extern "C" void kernel_launch(void* const* d_in, const int* in_sizes, int n_in,
                              void* d_out, int out_size, void* d_ws, size_t ws_size,
                              hipStream_t stream) {
    const float* x         = (const float*)d_in[0];
    const float* in_proj_w = (const float*)d_in[1];
    const float* conv_w    = (const float*)d_in[2];
    const float* conv_b    = (const float*)d_in[3];
    const float* x_proj_w  = (const float*)d_in[4];
    const float* dt_w      = (const float*)d_in[5];
    const float* dt_b      = (const float*)d_in[6];
    const float* A_log     = (const float*)d_in[7];
    const float* Dp        = (const float*)d_in[8];
    const float* ln_g      = (const float*)d_in[9];
    const float* ln_b      = (const float*)d_in[10];
    const float* gr_w      = (const float*)d_in[11];
    const float* gr_b      = (const float*)d_in[12];
    const float* cs_w      = (const float*)d_in[13];
    const float* cs_b      = (const float*)d_in[14];
    const float* out_proj_w= (const float*)d_in[15];
    float* out = (float*)d_out;

    float* ws    = (float*)d_ws;
    float* xz    = ws;                                   // 2*784*1536
    float* conv  = xz   + (long)Bb * Ll * 2 * DINn;      // 8*784*768
    float* xdbl  = conv + (long)Kk * BL * DINn;          // 4*1568*56
    float* delta = xdbl + (long)Kk * BL * Ee;            // 4*1568*768
    float* outy  = delta + (long)Kk * BL * DINn;         // 4*1568*768
    float* mu    = outy + (long)Kk * BL * DINn;          // 8*784
    float* rstd  = mu   + Kk * BL;
    float* gbuf  = rstd + Kk * BL;                       // 8*768
    float* attn  = gbuf + 2 * Kk * DINn;
    float* sbuf  = attn + 2 * Kk * DINn;                 // 2*784*768

    // 1) xz = x @ in_proj_w.T   (M=1568, N=1536, K=384)
    gemm_abt<<<dim3(1536 / BN, (BL + BM - 1) / BM, 1), 256, 0, stream>>>(
        x, in_proj_w, xz, BL, 2 * DINn, DMm, DMm, DMm, 2 * DINn,
        0, 0, 0, nullptr, 0, 0);

    // 2) depthwise conv + SiLU (gathered per direction)
    conv_kernel<<<dim3(Ll, Kk * Bb), 256, 0, stream>>>(xz, conv_w, conv_b, conv);

    // 3) x_dbl = conv @ x_proj_w.T  per k  (M=1568, N=56, K=768)
    gemm_abt<<<dim3(1, (BL + BM - 1) / BM, Kk), 256, 0, stream>>>(
        conv, x_proj_w, xdbl, BL, Ee, DINn, DINn, DINn, Ee,
        (long)BL * DINn, (long)Ee * DINn, (long)BL * Ee, nullptr, 0, 0);

    // 4) delta = softplus(dt @ dt_w.T + dt_b)  per k (M=1568, N=768, K=24)
    gemm_abt<<<dim3(DINn / BN, (BL + BM - 1) / BM, Kk), 256, 0, stream>>>(
        xdbl, dt_w, delta, BL, DINn, DTRr, Ee, DTRr, DINn,
        (long)BL * Ee, (long)DINn * DTRr, (long)BL * DINn, dt_b, DINn, 1);

    // 5) selective scan + gating + scatter (rev)
    scan_kernel<<<dim3((Kk * Bb * DINn * DSs) / 256), 256, 0, stream>>>(
        delta, conv, xdbl, A_log, Dp, xz, outy);

    // 6) LN stats per (kb,l)
    ln_stats_kernel<<<dim3(Ll, Kk * Bb), 256, 0, stream>>>(outy, mu, rstd);

    // 7) g vector per (kb,d)
    g_kernel<<<dim3(Kk * Bb), 768, 0, stream>>>(outy, mu, rstd, ln_g, ln_b, gbuf);

    // 8) attention vector per kb
    attn_kernel<<<dim3(Kk * Bb), 256, 0, stream>>>(gbuf, gr_w, gr_b, cs_w, cs_b, attn);

    // 9) weighted direction sum
    wsum_kernel<<<dim3((Bb * Ll * DINn + 255) / 256), 256, 0, stream>>>(outy, attn, sbuf);

    // 10) out = sbuf @ out_proj_w.T  (M=1568, N=384, K=768)
    gemm_abt<<<dim3(DMm / BN, (BL + BM - 1) / BM, 1), 256, 0, stream>>>(
        sbuf, out_proj_w, out, BL, DMm, DINn, DINn, DINn, DMm,
        0, 0, 0, nullptr, 0, 0);
}

// Round 2
// 675.038 us; speedup vs baseline: 1.7946x; 1.7946x over previous
//
#include <hip/hip_runtime.h>
#include <hip/hip_bf16.h>
#include <math.h>

// Problem constants (match reference)
#define Bb 2
#define Hh 28
#define Ww 28
#define Ll 784          // H*W
#define DMm 384
#define DINn 768        // DM*EXPAND
#define DSs 16
#define DTRr 24
#define Ee 56           // DTR + 2*DS
#define Kk 4
#define BL 1568         // B*L
#define NC 16           // scan chunks
#define CH 49           // chunk length (16*49 = 784)

// scan-position mapping: spatial index p for scan index l, direction k
__device__ __forceinline__ int spos(int k, int l) {
    if (k == 0) return l;
    if (k == 1) return (l % 28) * 28 + l / 28;
    if (k == 3) l = 783 - l;
    int j = l % 7;
    int i = (l / 7) % 7;
    int wg = (l / 49) % 4;
    int hg = l / 196;
    return (hg * 7 + i) * 28 + wg * 7 + j;
}

// ---------------- Generic tiled GEMM: C[m,n] = epi( sum_k A[m,k]*B[n,k] ) ----------------
#define BM 64
#define BN 64
#define BKk 16

__global__ __launch_bounds__(256) void gemm_abt(
    const float* __restrict__ A, const float* __restrict__ B, float* __restrict__ C,
    int M, int N, int K, int lda, int ldb, int ldc,
    long sA, long sB, long sC,
    const float* __restrict__ bias, long sBias, int epi)
{
    int z = blockIdx.z;
    A += (long)z * sA; B += (long)z * sB; C += (long)z * sC;
    if (bias) bias += (long)z * sBias;
    int n0 = blockIdx.x * BN;
    int m0 = blockIdx.y * BM;
    __shared__ float As[BKk][BM];
    __shared__ float Bs[BKk][BN];
    int t = threadIdx.x;
    int tx = t & 15, ty = t >> 4;
    float acc[4][4] = {};
    for (int k0 = 0; k0 < K; k0 += BKk) {
#pragma unroll
        for (int i = 0; i < 4; ++i) {
            int r = (t >> 4) + 16 * i;
            int k = t & 15;
            float va = 0.f, vb = 0.f;
            if (m0 + r < M && k0 + k < K) va = A[(long)(m0 + r) * lda + k0 + k];
            if (n0 + r < N && k0 + k < K) vb = B[(long)(n0 + r) * ldb + k0 + k];
            As[k][r] = va;
            Bs[k][r] = vb;
        }
        __syncthreads();
#pragma unroll
        for (int kk = 0; kk < BKk; ++kk) {
            float a[4], b[4];
#pragma unroll
            for (int i = 0; i < 4; ++i) a[i] = As[kk][ty * 4 + i];
#pragma unroll
            for (int j = 0; j < 4; ++j) b[j] = Bs[kk][tx * 4 + j];
#pragma unroll
            for (int i = 0; i < 4; ++i)
#pragma unroll
                for (int j = 0; j < 4; ++j)
                    acc[i][j] += a[i] * b[j];
        }
        __syncthreads();
    }
#pragma unroll
    for (int i = 0; i < 4; ++i) {
        int m = m0 + ty * 4 + i;
        if (m >= M) continue;
#pragma unroll
        for (int j = 0; j < 4; ++j) {
            int n = n0 + tx * 4 + j;
            if (n >= N) continue;
            float v = acc[i][j];
            if (epi == 1) {
                v += bias[n];
                v = fmaxf(v, 0.f) + log1pf(expf(-fabsf(v)));  // softplus, stable
            }
            C[(long)m * ldc + n] = v;
        }
    }
}

// ---------------- depthwise causal conv (k=4) + SiLU, with scan gather ----------------
__global__ __launch_bounds__(256) void conv_kernel(
    const float* __restrict__ xz, const float* __restrict__ conv_w,
    const float* __restrict__ conv_b, float* __restrict__ conv)
{
    int l = blockIdx.x;
    int kb = blockIdx.y;       // k*2 + b
    int k = kb >> 1, b = kb & 1;
    int p[4];
#pragma unroll
    for (int j = 0; j < 4; ++j) {
        int lp = l - 3 + j;
        p[j] = (lp >= 0) ? spos(k, lp) : -1;
    }
    for (int d = threadIdx.x; d < DINn; d += 256) {
        float acc = conv_b[k * DINn + d];
        const float* w = conv_w + (long)(k * DINn + d) * 4;
#pragma unroll
        for (int j = 0; j < 4; ++j) {
            if (p[j] >= 0)
                acc += w[j] * xz[((long)b * Ll + p[j]) * (2 * DINn) + d];
        }
        acc = acc / (1.f + __expf(-acc));   // SiLU
        conv[((long)kb * Ll + l) * DINn + d] = acc;
    }
}

// ---------------- chunked selective scan, pass 1: per-chunk (A,B) transfer ----------------
// thread t: n = t&15, c = (t>>4)&15, q = t>>8 (q = kb*DIN + d)
__global__ __launch_bounds__(256) void scan1_kernel(
    const float* __restrict__ delta, const float* __restrict__ conv,
    const float* __restrict__ xdbl, const float* __restrict__ A_log,
    float* __restrict__ chunkA, float* __restrict__ chunkB)
{
    int t = blockIdx.x * 256 + threadIdx.x;     // 0 .. 8*768*16*16-1
    int n = t & 15;
    int c = (t >> 4) & (NC - 1);
    int q = t >> 8;                             // kb*768 + d
    int d = q % DINn;
    int kb = q / DINn;
    int k = kb >> 1;

    float An = -__expf(A_log[((long)k * DINn + d) * DSs + n]);
    const float* dl = delta + (long)kb * Ll * DINn + d;
    const float* cl = conv + (long)kb * Ll * DINn + d;
    const float* xd = xdbl + (long)kb * Ll * Ee;
    int l0 = c * CH;
    float h = 0.f, sumde = 0.f;
    for (int i = 0; i < CH; ++i) {
        int l = l0 + i;
        float de = dl[(long)l * DINn];
        float cv = cl[(long)l * DINn];
        float Bv = xd[(long)l * Ee + DTRr + n];
        sumde += de;
        h = __expf(de * An) * h + de * cv * Bv;
    }
    chunkA[t] = __expf(An * sumde);
    chunkB[t] = h;
}

// ---------------- pass 1.5: serial combine of chunk states ----------------
__global__ __launch_bounds__(256) void scanfix_kernel(
    const float* __restrict__ chunkA, const float* __restrict__ chunkB,
    float* __restrict__ hin)
{
    int u = blockIdx.x * 256 + threadIdx.x;   // 0..98303  (kb*768+d)*16+n
    int n = u & 15;
    int q = u >> 4;
    float h = 0.f;
#pragma unroll
    for (int c = 0; c < NC; ++c) {
        int idx = (q * NC + c) * 16 + n;
        hin[idx] = h;
        h = chunkA[idx] * h + chunkB[idx];
    }
}

// ---------------- pass 2: local scan from hin, C-reduce, gate, scatter ----------------
__global__ __launch_bounds__(256) void scan2_kernel(
    const float* __restrict__ delta, const float* __restrict__ conv,
    const float* __restrict__ xdbl, const float* __restrict__ A_log,
    const float* __restrict__ Dp, const float* __restrict__ xz,
    const float* __restrict__ hin, float* __restrict__ outy)
{
    int t = blockIdx.x * 256 + threadIdx.x;
    int n = t & 15;
    int c = (t >> 4) & (NC - 1);
    int q = t >> 8;
    int d = q % DINn;
    int kb = q / DINn;
    int k = kb >> 1, b = kb & 1;

    float An = -__expf(A_log[((long)k * DINn + d) * DSs + n]);
    float Dv = Dp[k * DINn + d];
    const float* dl = delta + (long)kb * Ll * DINn + d;
    const float* cl = conv + (long)kb * Ll * DINn + d;
    const float* xd = xdbl + (long)kb * Ll * Ee;
    int l0 = c * CH;
    float h = hin[t];
    for (int i = 0; i < CH; ++i) {
        int l = l0 + i;
        float de = dl[(long)l * DINn];
        float cv = cl[(long)l * DINn];
        float Bv = xd[(long)l * Ee + DTRr + n];
        float Cv = xd[(long)l * Ee + DTRr + DSs + n];
        h = __expf(de * An) * h + de * cv * Bv;
        float contrib = h * Cv;
        contrib += __shfl_xor(contrib, 1);
        contrib += __shfl_xor(contrib, 2);
        contrib += __shfl_xor(contrib, 4);
        contrib += __shfl_xor(contrib, 8);
        if (n == 0) {
            float y = contrib + Dv * cv;
            int p = spos(k, l);
            float zv = xz[((long)b * Ll + p) * (2 * DINn) + DINn + d];
            y *= zv / (1.f + __expf(-zv));
            outy[((long)kb * Ll + p) * DINn + d] = y;
        }
    }
}

// ---------------- LayerNorm stats per (kb, l) ----------------
__global__ __launch_bounds__(256) void ln_stats_kernel(
    const float* __restrict__ outy, float* __restrict__ mu, float* __restrict__ rstd)
{
    int l = blockIdx.x, kb = blockIdx.y;
    const float* row = outy + ((long)kb * Ll + l) * DINn;
    float s = 0.f, ss = 0.f;
    for (int d = threadIdx.x; d < DINn; d += 256) {
        float v = row[d];
        s += v; ss += v * v;
    }
#pragma unroll
    for (int o = 32; o > 0; o >>= 1) {
        s += __shfl_down(s, o);
        ss += __shfl_down(ss, o);
    }
    __shared__ float sh[8];
    int wid = threadIdx.x >> 6;
    if ((threadIdx.x & 63) == 0) { sh[wid] = s; sh[wid + 4] = ss; }
    __syncthreads();
    if (threadIdx.x == 0) {
        s = sh[0] + sh[1] + sh[2] + sh[3];
        ss = sh[4] + sh[5] + sh[6] + sh[7];
        float m = s / DINn;
        float var = ss / DINn - m * m;
        mu[(long)kb * Ll + l] = m;
        rstd[(long)kb * Ll + l] = rsqrtf(var + 1e-5f);
    }
}

// ---------------- partial g: gpart[kb][c][d] over l-chunks ----------------
__global__ __launch_bounds__(768) void gpart_kernel(
    const float* __restrict__ outy, const float* __restrict__ mu,
    const float* __restrict__ rstd, float* __restrict__ gpart)
{
    int kb = blockIdx.x;
    int c = blockIdx.y;
    int d = threadIdx.x;
    float acc = 0.f;
    int l0 = c * CH;
    for (int i = 0; i < CH; ++i) {
        int l = l0 + i;
        float v = outy[((long)kb * Ll + l) * DINn + d];
        acc += (v - mu[(long)kb * Ll + l]) * rstd[(long)kb * Ll + l];
    }
    gpart[((long)kb * NC + c) * DINn + d] = acc;
}

// ---------------- attn[kb][d] = sigmoid(cs(gelu(gr(g)))) ----------------
__global__ __launch_bounds__(256) void attn_kernel(
    const float* __restrict__ gpart, const float* __restrict__ ln_g,
    const float* __restrict__ ln_b, const float* __restrict__ gr_w,
    const float* __restrict__ gr_b, const float* __restrict__ cs_w,
    const float* __restrict__ cs_b, float* __restrict__ attn)
{
    __shared__ float gs[DINn];
    __shared__ float hs[96];
    int kb = blockIdx.x;
    int t = threadIdx.x;
    for (int d = t; d < DINn; d += 256) {
        float s = 0.f;
#pragma unroll
        for (int c = 0; c < NC; ++c)
            s += gpart[((long)kb * NC + c) * DINn + d];
        gs[d] = ln_g[d] * (s / (float)Ll) + ln_b[d];
    }
    __syncthreads();
    if (t < 96) {
        float a = gr_b[t];
        const float* wrow = gr_w + (long)t * DINn;
        for (int d = 0; d < DINn; ++d) a += wrow[d] * gs[d];
        hs[t] = 0.5f * a * (1.f + erff(a * 0.70710678118654752f));  // exact gelu
    }
    __syncthreads();
    for (int d = t; d < DINn; d += 256) {
        float a = cs_b[d];
        const float* wrow = cs_w + (long)d * 96;
        for (int e = 0; e < 96; ++e) a += wrow[e] * hs[e];
        attn[kb * DINn + d] = 1.f / (1.f + expf(-a));
    }
}

// ---------------- weighted sum over directions ----------------
__global__ __launch_bounds__(256) void wsum_kernel(
    const float* __restrict__ outy, const float* __restrict__ attn,
    float* __restrict__ sbuf)
{
    long idx = (long)blockIdx.x * 256 + threadIdx.x;   // over B*L*DIN
    if (idx >= (long)Bb * Ll * DINn) return;
    int d = idx % DINn;
    long bl = idx / DINn;          // b*L + p
    int b = (int)(bl / Ll);
    float acc = 0.f;
#pragma unroll
    for (int k = 0; k < Kk; ++k) {
        int kb = k * 2 + b;
        acc += outy[((long)kb * Ll + (bl % Ll)) * DINn + d] * attn[kb * DINn + d];
    }
    sbuf[idx] = acc;
}

extern "C" void kernel_launch(void* const* d_in, const int* in_sizes, int n_in,
                              void* d_out, int out_size, void* d_ws, size_t ws_size,
                              hipStream_t stream) {
    const float* x         = (const float*)d_in[0];
    const float* in_proj_w = (const float*)d_in[1];
    const float* conv_w    = (const float*)d_in[2];
    const float* conv_b    = (const float*)d_in[3];
    const float* x_proj_w  = (const float*)d_in[4];
    const float* dt_w      = (const float*)d_in[5];
    const float* dt_b      = (const float*)d_in[6];
    const float* A_log     = (const float*)d_in[7];
    const float* Dp        = (const float*)d_in[8];
    const float* ln_g      = (const float*)d_in[9];
    const float* ln_b      = (const float*)d_in[10];
    const float* gr_w      = (const float*)d_in[11];
    const float* gr_b      = (const float*)d_in[12];
    const float* cs_w      = (const float*)d_in[13];
    const float* cs_b      = (const float*)d_in[14];
    const float* out_proj_w= (const float*)d_in[15];
    float* out = (float*)d_out;

    float* ws    = (float*)d_ws;
    float* xz    = ws;                                   // 2*784*1536
    float* conv  = xz   + (long)Bb * Ll * 2 * DINn;      // 8*784*768
    float* xdbl  = conv + (long)Kk * BL * DINn;          // 8*784*56
    float* delta = xdbl + (long)Kk * BL * Ee;            // 8*784*768
    float* outy  = delta + (long)Kk * BL * DINn;         // 8*784*768
    float* mu    = outy + (long)Kk * BL * DINn;          // 8*784
    float* rstd  = mu   + Kk * BL;
    float* gpart = rstd + Kk * BL;                       // 8*16*768
    float* attn  = gpart + (long)Kk * Bb * NC * DINn;    // 8*768
    float* sbuf  = attn + 2 * Kk * DINn;                 // 2*784*768
    float* chunkA= sbuf + (long)Bb * Ll * DINn;          // 8*768*16*16
    float* chunkB= chunkA + (long)Kk * Bb * DINn * NC * DSs;
    float* hin   = chunkB + (long)Kk * Bb * DINn * NC * DSs;

    // 1) xz = x @ in_proj_w.T   (M=1568, N=1536, K=384)
    gemm_abt<<<dim3(1536 / BN, (BL + BM - 1) / BM, 1), 256, 0, stream>>>(
        x, in_proj_w, xz, BL, 2 * DINn, DMm, DMm, DMm, 2 * DINn,
        0, 0, 0, nullptr, 0, 0);

    // 2) depthwise conv + SiLU (gathered per direction)
    conv_kernel<<<dim3(Ll, Kk * Bb), 256, 0, stream>>>(xz, conv_w, conv_b, conv);

    // 3) x_dbl = conv @ x_proj_w.T  per k  (M=1568, N=56, K=768)
    gemm_abt<<<dim3(1, (BL + BM - 1) / BM, Kk), 256, 0, stream>>>(
        conv, x_proj_w, xdbl, BL, Ee, DINn, DINn, DINn, Ee,
        (long)BL * DINn, (long)Ee * DINn, (long)BL * Ee, nullptr, 0, 0);

    // 4) delta = softplus(dt @ dt_w.T + dt_b)  per k (M=1568, N=768, K=24)
    gemm_abt<<<dim3(DINn / BN, (BL + BM - 1) / BM, Kk), 256, 0, stream>>>(
        xdbl, dt_w, delta, BL, DINn, DTRr, Ee, DTRr, DINn,
        (long)BL * Ee, (long)DINn * DTRr, (long)BL * DINn, dt_b, DINn, 1);

    // 5) chunked selective scan
    int scan_threads = Kk * Bb * DINn * NC * DSs;       // 1,572,864
    scan1_kernel<<<dim3(scan_threads / 256), 256, 0, stream>>>(
        delta, conv, xdbl, A_log, chunkA, chunkB);
    scanfix_kernel<<<dim3((Kk * Bb * DINn * DSs) / 256), 256, 0, stream>>>(
        chunkA, chunkB, hin);
    scan2_kernel<<<dim3(scan_threads / 256), 256, 0, stream>>>(
        delta, conv, xdbl, A_log, Dp, xz, hin, outy);

    // 6) LN stats per (kb,l)
    ln_stats_kernel<<<dim3(Ll, Kk * Bb), 256, 0, stream>>>(outy, mu, rstd);

    // 7) partial g per (kb, l-chunk)
    gpart_kernel<<<dim3(Kk * Bb, NC), 768, 0, stream>>>(outy, mu, rstd, gpart);

    // 8) attention vector per kb
    attn_kernel<<<dim3(Kk * Bb), 256, 0, stream>>>(
        gpart, ln_g, ln_b, gr_w, gr_b, cs_w, cs_b, attn);

    // 9) weighted direction sum
    wsum_kernel<<<dim3((Bb * Ll * DINn + 255) / 256), 256, 0, stream>>>(outy, attn, sbuf);

    // 10) out = sbuf @ out_proj_w.T  (M=1568, N=384, K=768)
    gemm_abt<<<dim3(DMm / BN, (BL + BM - 1) / BM, 1), 256, 0, stream>>>(
        sbuf, out_proj_w, out, BL, DMm, DINn, DINn, DINn, DMm,
        0, 0, 0, nullptr, 0, 0);
}

// Round 3
// 450.125 us; speedup vs baseline: 2.6913x; 1.4997x over previous
//
#include <hip/hip_runtime.h>
#include <hip/hip_bf16.h>
#include <math.h>

// Problem constants (match reference)
#define Bb 2
#define Hh 28
#define Ww 28
#define Ll 784          // H*W
#define DMm 384
#define DINn 768        // DM*EXPAND
#define DSs 16
#define DTRr 24
#define Ee 56           // DTR + 2*DS
#define Kk 4
#define BL 1568         // B*L
#define NC 28           // scan chunks
#define CH 28           // chunk length (28*28 = 784)

// scan-position mapping: spatial index p for scan index l, direction k
__device__ __forceinline__ int spos(int k, int l) {
    if (k == 0) return l;
    if (k == 1) return (l % 28) * 28 + l / 28;
    if (k == 3) l = 783 - l;
    int j = l % 7;
    int i = (l / 7) % 7;
    int wg = (l / 49) % 4;
    int hg = l / 196;
    return (hg * 7 + i) * 28 + wg * 7 + j;
}

// ---------------- Generic tiled GEMM: C[m,n] = epi( sum_k A[m,k]*B[n,k] ) ----------------
#define BM 64
#define BN 64
#define BKk 16

__global__ __launch_bounds__(256) void gemm_abt(
    const float* __restrict__ A, const float* __restrict__ B, float* __restrict__ C,
    int M, int N, int K, int lda, int ldb, int ldc,
    long sA, long sB, long sC,
    const float* __restrict__ bias, long sBias, int epi)
{
    int z = blockIdx.z;
    A += (long)z * sA; B += (long)z * sB; C += (long)z * sC;
    if (bias) bias += (long)z * sBias;
    int n0 = blockIdx.x * BN;
    int m0 = blockIdx.y * BM;
    __shared__ float As[BKk][BM];
    __shared__ float Bs[BKk][BN];
    int t = threadIdx.x;
    int tx = t & 15, ty = t >> 4;
    float acc[4][4] = {};
    for (int k0 = 0; k0 < K; k0 += BKk) {
#pragma unroll
        for (int i = 0; i < 4; ++i) {
            int r = (t >> 4) + 16 * i;
            int k = t & 15;
            float va = 0.f, vb = 0.f;
            if (m0 + r < M && k0 + k < K) va = A[(long)(m0 + r) * lda + k0 + k];
            if (n0 + r < N && k0 + k < K) vb = B[(long)(n0 + r) * ldb + k0 + k];
            As[k][r] = va;
            Bs[k][r] = vb;
        }
        __syncthreads();
#pragma unroll
        for (int kk = 0; kk < BKk; ++kk) {
            float a[4], b[4];
#pragma unroll
            for (int i = 0; i < 4; ++i) a[i] = As[kk][ty * 4 + i];
#pragma unroll
            for (int j = 0; j < 4; ++j) b[j] = Bs[kk][tx * 4 + j];
#pragma unroll
            for (int i = 0; i < 4; ++i)
#pragma unroll
                for (int j = 0; j < 4; ++j)
                    acc[i][j] += a[i] * b[j];
        }
        __syncthreads();
    }
#pragma unroll
    for (int i = 0; i < 4; ++i) {
        int m = m0 + ty * 4 + i;
        if (m >= M) continue;
#pragma unroll
        for (int j = 0; j < 4; ++j) {
            int n = n0 + tx * 4 + j;
            if (n >= N) continue;
            float v = acc[i][j];
            if (epi == 1) {
                v += bias[n];
                v = fmaxf(v, 0.f) + log1pf(expf(-fabsf(v)));  // softplus, stable
            }
            C[(long)m * ldc + n] = v;
        }
    }
}

// ---------------- depthwise causal conv (k=4) + SiLU, with scan gather ----------------
__global__ __launch_bounds__(256) void conv_kernel(
    const float* __restrict__ xz, const float* __restrict__ conv_w,
    const float* __restrict__ conv_b, float* __restrict__ conv)
{
    int l = blockIdx.x;
    int kb = blockIdx.y;       // k*2 + b
    int k = kb >> 1, b = kb & 1;
    int p[4];
#pragma unroll
    for (int j = 0; j < 4; ++j) {
        int lp = l - 3 + j;
        p[j] = (lp >= 0) ? spos(k, lp) : -1;
    }
    for (int d = threadIdx.x; d < DINn; d += 256) {
        float acc = conv_b[k * DINn + d];
        const float* w = conv_w + (long)(k * DINn + d) * 4;
#pragma unroll
        for (int j = 0; j < 4; ++j) {
            if (p[j] >= 0)
                acc += w[j] * xz[((long)b * Ll + p[j]) * (2 * DINn) + d];
        }
        acc = acc / (1.f + __expf(-acc));   // SiLU
        conv[((long)kb * Ll + l) * DINn + d] = acc;
    }
}

// ---------------- chunked selective scan, pass 1: per-chunk (A,B) transfer ----------------
// thread = (kb, chunk c, d); d fastest across lanes; all 16 states in registers.
// chunkA/chunkB layout: [kb][c][n][d]
__global__ __launch_bounds__(256) void scan1_kernel(
    const float* __restrict__ delta, const float* __restrict__ conv,
    const float* __restrict__ xdbl, const float* __restrict__ A_log,
    float* __restrict__ chunkA, float* __restrict__ chunkB)
{
    int d = blockIdx.x * 256 + threadIdx.x;
    int c = blockIdx.y;
    int kb = blockIdx.z;
    int k = kb >> 1;

    __shared__ float bc[CH * 32];   // B rows (16) + C rows (16) per l
    const float* xd = xdbl + ((long)kb * Ll + c * CH) * Ee;
    for (int u = threadIdx.x; u < CH * 32; u += 256) {
        int i = u >> 5, j = u & 31;
        bc[u] = xd[i * Ee + DTRr + j];
    }
    __syncthreads();

    float An[DSs], h[DSs];
#pragma unroll
    for (int n = 0; n < DSs; ++n) {
        An[n] = -__expf(A_log[((long)k * DINn + d) * DSs + n]);
        h[n] = 0.f;
    }
    const float* dl = delta + ((long)kb * Ll + c * CH) * DINn + d;
    const float* cl = conv + ((long)kb * Ll + c * CH) * DINn + d;
    float sumde = 0.f;
    for (int i = 0; i < CH; ++i) {
        float de = dl[(long)i * DINn];
        float cv = cl[(long)i * DINn];
        sumde += de;
        float dexc = de * cv;
#pragma unroll
        for (int n = 0; n < DSs; ++n)
            h[n] = __expf(de * An[n]) * h[n] + dexc * bc[i * 32 + n];
    }
    long o = (long)(kb * NC + c) * DSs * DINn + d;
#pragma unroll
    for (int n = 0; n < DSs; ++n) {
        chunkA[o + (long)n * DINn] = __expf(An[n] * sumde);
        chunkB[o + (long)n * DINn] = h[n];
    }
}

// ---------------- pass 1.5: serial combine of chunk states ----------------
// thread = (kb, n, d), d fastest; loops over chunks
__global__ __launch_bounds__(256) void scanfix_kernel(
    const float* __restrict__ chunkA, const float* __restrict__ chunkB,
    float* __restrict__ hin)
{
    int u = blockIdx.x * 256 + threadIdx.x;   // 0..98303
    int d = u % DINn;
    int rest = u / DINn;                      // kb*16 + n
    int n = rest & 15;
    int kb = rest >> 4;
    float h = 0.f;
#pragma unroll
    for (int c = 0; c < NC; ++c) {
        long idx = ((long)(kb * NC + c) * DSs + n) * DINn + d;
        hin[idx] = h;
        h = chunkA[idx] * h + chunkB[idx];
    }
}

// ---------------- pass 2: local scan from hin, in-register C-reduce, gate, scatter ----------------
__global__ __launch_bounds__(256) void scan2_kernel(
    const float* __restrict__ delta, const float* __restrict__ conv,
    const float* __restrict__ xdbl, const float* __restrict__ A_log,
    const float* __restrict__ Dp, const float* __restrict__ xz,
    const float* __restrict__ hin, float* __restrict__ outy)
{
    int d = blockIdx.x * 256 + threadIdx.x;
    int c = blockIdx.y;
    int kb = blockIdx.z;
    int k = kb >> 1, b = kb & 1;

    __shared__ float bc[CH * 32];
    const float* xd = xdbl + ((long)kb * Ll + c * CH) * Ee;
    for (int u = threadIdx.x; u < CH * 32; u += 256) {
        int i = u >> 5, j = u & 31;
        bc[u] = xd[i * Ee + DTRr + j];
    }
    __syncthreads();

    float An[DSs], h[DSs];
    long o = (long)(kb * NC + c) * DSs * DINn + d;
#pragma unroll
    for (int n = 0; n < DSs; ++n) {
        An[n] = -__expf(A_log[((long)k * DINn + d) * DSs + n]);
        h[n] = hin[o + (long)n * DINn];
    }
    float Dv = Dp[k * DINn + d];
    const float* dl = delta + ((long)kb * Ll + c * CH) * DINn + d;
    const float* cl = conv + ((long)kb * Ll + c * CH) * DINn + d;
    for (int i = 0; i < CH; ++i) {
        float de = dl[(long)i * DINn];
        float cv = cl[(long)i * DINn];
        float dexc = de * cv;
        float y = 0.f;
#pragma unroll
        for (int n = 0; n < DSs; ++n) {
            h[n] = __expf(de * An[n]) * h[n] + dexc * bc[i * 32 + n];
            y += h[n] * bc[i * 32 + 16 + n];
        }
        y += Dv * cv;
        int l = c * CH + i;
        int p = spos(k, l);
        float zv = xz[((long)b * Ll + p) * (2 * DINn) + DINn + d];
        y *= zv / (1.f + __expf(-zv));
        outy[((long)kb * Ll + p) * DINn + d] = y;
    }
}

// ---------------- LayerNorm stats per (kb, l) ----------------
__global__ __launch_bounds__(256) void ln_stats_kernel(
    const float* __restrict__ outy, float* __restrict__ mu, float* __restrict__ rstd)
{
    int l = blockIdx.x, kb = blockIdx.y;
    const float* row = outy + ((long)kb * Ll + l) * DINn;
    float s = 0.f, ss = 0.f;
    for (int d = threadIdx.x; d < DINn; d += 256) {
        float v = row[d];
        s += v; ss += v * v;
    }
#pragma unroll
    for (int o = 32; o > 0; o >>= 1) {
        s += __shfl_down(s, o);
        ss += __shfl_down(ss, o);
    }
    __shared__ float sh[8];
    int wid = threadIdx.x >> 6;
    if ((threadIdx.x & 63) == 0) { sh[wid] = s; sh[wid + 4] = ss; }
    __syncthreads();
    if (threadIdx.x == 0) {
        s = sh[0] + sh[1] + sh[2] + sh[3];
        ss = sh[4] + sh[5] + sh[6] + sh[7];
        float m = s / DINn;
        float var = ss / DINn - m * m;
        mu[(long)kb * Ll + l] = m;
        rstd[(long)kb * Ll + l] = rsqrtf(var + 1e-5f);
    }
}

// ---------------- partial g: gpart[kb][c][d] over l-chunks ----------------
__global__ __launch_bounds__(768) void gpart_kernel(
    const float* __restrict__ outy, const float* __restrict__ mu,
    const float* __restrict__ rstd, float* __restrict__ gpart)
{
    int kb = blockIdx.x;
    int c = blockIdx.y;
    int d = threadIdx.x;
    float acc = 0.f;
    int l0 = c * CH;
    for (int i = 0; i < CH; ++i) {
        int l = l0 + i;
        float v = outy[((long)kb * Ll + l) * DINn + d];
        acc += (v - mu[(long)kb * Ll + l]) * rstd[(long)kb * Ll + l];
    }
    gpart[((long)kb * NC + c) * DINn + d] = acc;
}

// ---------------- attn[kb][d] = sigmoid(cs(gelu(gr(g)))) ----------------
__global__ __launch_bounds__(256) void attn_kernel(
    const float* __restrict__ gpart, const float* __restrict__ ln_g,
    const float* __restrict__ ln_b, const float* __restrict__ gr_w,
    const float* __restrict__ gr_b, const float* __restrict__ cs_w,
    const float* __restrict__ cs_b, float* __restrict__ attn)
{
    __shared__ float gs[DINn];
    __shared__ float hs[96];
    int kb = blockIdx.x;
    int t = threadIdx.x;
    for (int d = t; d < DINn; d += 256) {
        float s = 0.f;
#pragma unroll
        for (int c = 0; c < NC; ++c)
            s += gpart[((long)kb * NC + c) * DINn + d];
        gs[d] = ln_g[d] * (s / (float)Ll) + ln_b[d];
    }
    __syncthreads();
    if (t < 96) {
        float a = gr_b[t];
        const float* wrow = gr_w + (long)t * DINn;
        for (int d = 0; d < DINn; ++d) a += wrow[d] * gs[d];
        hs[t] = 0.5f * a * (1.f + erff(a * 0.70710678118654752f));  // exact gelu
    }
    __syncthreads();
    for (int d = t; d < DINn; d += 256) {
        float a = cs_b[d];
        const float* wrow = cs_w + (long)d * 96;
        for (int e = 0; e < 96; ++e) a += wrow[e] * hs[e];
        attn[kb * DINn + d] = 1.f / (1.f + __expf(-a));
    }
}

// ---------------- weighted sum over directions ----------------
__global__ __launch_bounds__(256) void wsum_kernel(
    const float* __restrict__ outy, const float* __restrict__ attn,
    float* __restrict__ sbuf)
{
    long idx = (long)blockIdx.x * 256 + threadIdx.x;   // over B*L*DIN
    if (idx >= (long)Bb * Ll * DINn) return;
    int d = idx % DINn;
    long bl = idx / DINn;          // b*L + p
    int b = (int)(bl / Ll);
    float acc = 0.f;
#pragma unroll
    for (int k = 0; k < Kk; ++k) {
        int kb = k * 2 + b;
        acc += outy[((long)kb * Ll + (bl % Ll)) * DINn + d] * attn[kb * DINn + d];
    }
    sbuf[idx] = acc;
}

extern "C" void kernel_launch(void* const* d_in, const int* in_sizes, int n_in,
                              void* d_out, int out_size, void* d_ws, size_t ws_size,
                              hipStream_t stream) {
    const float* x         = (const float*)d_in[0];
    const float* in_proj_w = (const float*)d_in[1];
    const float* conv_w    = (const float*)d_in[2];
    const float* conv_b    = (const float*)d_in[3];
    const float* x_proj_w  = (const float*)d_in[4];
    const float* dt_w      = (const float*)d_in[5];
    const float* dt_b      = (const float*)d_in[6];
    const float* A_log     = (const float*)d_in[7];
    const float* Dp        = (const float*)d_in[8];
    const float* ln_g      = (const float*)d_in[9];
    const float* ln_b      = (const float*)d_in[10];
    const float* gr_w      = (const float*)d_in[11];
    const float* gr_b      = (const float*)d_in[12];
    const float* cs_w      = (const float*)d_in[13];
    const float* cs_b      = (const float*)d_in[14];
    const float* out_proj_w= (const float*)d_in[15];
    float* out = (float*)d_out;

    float* ws    = (float*)d_ws;
    float* xz    = ws;                                   // 2*784*1536
    float* conv  = xz   + (long)Bb * Ll * 2 * DINn;      // 8*784*768
    float* xdbl  = conv + (long)Kk * BL * DINn;          // 8*784*56
    float* delta = xdbl + (long)Kk * BL * Ee;            // 8*784*768
    float* outy  = delta + (long)Kk * BL * DINn;         // 8*784*768
    float* mu    = outy + (long)Kk * BL * DINn;          // 8*784
    float* rstd  = mu   + Kk * BL;
    float* gpart = rstd + Kk * BL;                       // 8*NC*768
    float* attn  = gpart + (long)Kk * Bb * NC * DINn;    // 8*768
    float* sbuf  = attn + 2 * Kk * DINn;                 // 2*784*768
    float* chunkA= sbuf + (long)Bb * Ll * DINn;          // 8*NC*16*768
    float* chunkB= chunkA + (long)Kk * Bb * NC * DSs * DINn;
    float* hin   = chunkB + (long)Kk * Bb * NC * DSs * DINn;

    // 1) xz = x @ in_proj_w.T   (M=1568, N=1536, K=384)
    gemm_abt<<<dim3(1536 / BN, (BL + BM - 1) / BM, 1), 256, 0, stream>>>(
        x, in_proj_w, xz, BL, 2 * DINn, DMm, DMm, DMm, 2 * DINn,
        0, 0, 0, nullptr, 0, 0);

    // 2) depthwise conv + SiLU (gathered per direction)
    conv_kernel<<<dim3(Ll, Kk * Bb), 256, 0, stream>>>(xz, conv_w, conv_b, conv);

    // 3) x_dbl = conv @ x_proj_w.T  per k  (M=1568, N=56, K=768)
    gemm_abt<<<dim3(1, (BL + BM - 1) / BM, Kk), 256, 0, stream>>>(
        conv, x_proj_w, xdbl, BL, Ee, DINn, DINn, DINn, Ee,
        (long)BL * DINn, (long)Ee * DINn, (long)BL * Ee, nullptr, 0, 0);

    // 4) delta = softplus(dt @ dt_w.T + dt_b)  per k (M=1568, N=768, K=24)
    gemm_abt<<<dim3(DINn / BN, (BL + BM - 1) / BM, Kk), 256, 0, stream>>>(
        xdbl, dt_w, delta, BL, DINn, DTRr, Ee, DTRr, DINn,
        (long)BL * Ee, (long)DINn * DTRr, (long)BL * DINn, dt_b, DINn, 1);

    // 5) chunked selective scan (d fastest across lanes, 16 states in registers)
    scan1_kernel<<<dim3(DINn / 256, NC, Kk * Bb), 256, 0, stream>>>(
        delta, conv, xdbl, A_log, chunkA, chunkB);
    scanfix_kernel<<<dim3((Kk * Bb * DSs * DINn) / 256), 256, 0, stream>>>(
        chunkA, chunkB, hin);
    scan2_kernel<<<dim3(DINn / 256, NC, Kk * Bb), 256, 0, stream>>>(
        delta, conv, xdbl, A_log, Dp, xz, hin, outy);

    // 6) LN stats per (kb,l)
    ln_stats_kernel<<<dim3(Ll, Kk * Bb), 256, 0, stream>>>(outy, mu, rstd);

    // 7) partial g per (kb, l-chunk)
    gpart_kernel<<<dim3(Kk * Bb, NC), 768, 0, stream>>>(outy, mu, rstd, gpart);

    // 8) attention vector per kb
    attn_kernel<<<dim3(Kk * Bb), 256, 0, stream>>>(
        gpart, ln_g, ln_b, gr_w, gr_b, cs_w, cs_b, attn);

    // 9) weighted direction sum
    wsum_kernel<<<dim3((Bb * Ll * DINn + 255) / 256), 256, 0, stream>>>(outy, attn, sbuf);

    // 10) out = sbuf @ out_proj_w.T  (M=1568, N=384, K=768)
    gemm_abt<<<dim3(DMm / BN, (BL + BM - 1) / BM, 1), 256, 0, stream>>>(
        sbuf, out_proj_w, out, BL, DMm, DINn, DINn, DINn, DMm,
        0, 0, 0, nullptr, 0, 0);
}

// Round 4
// 359.008 us; speedup vs baseline: 3.3744x; 1.2538x over previous
//
#include <hip/hip_runtime.h>
#include <hip/hip_bf16.h>
#include <math.h>

// Problem constants (match reference)
#define Bb 2
#define Hh 28
#define Ww 28
#define Ll 784          // H*W
#define DMm 384
#define DINn 768        // DM*EXPAND
#define DSs 16
#define DTRr 24
#define Ee 56           // DTR + 2*DS
#define Kk 4
#define BL 1568         // B*L
#define NC 28           // scan chunks
#define CH 28           // chunk length (28*28 = 784)

// scan-position mapping: spatial index p for scan index l, direction k
__device__ __forceinline__ int spos(int k, int l) {
    if (k == 0) return l;
    if (k == 1) return (l % 28) * 28 + l / 28;
    if (k == 3) l = 783 - l;
    int j = l % 7;
    int i = (l / 7) % 7;
    int wg = (l / 49) % 4;
    int hg = l / 196;
    return (hg * 7 + i) * 28 + wg * 7 + j;
}

__device__ __forceinline__ float softplusf(float x) {
    return fmaxf(x, 0.f) + log1pf(__expf(-fabsf(x)));
}

// ---------------- prefetching tiled GEMM: C[m,n] = sum_k A[m,k]*B[n,k] ----------------
// 256 threads as 16x16; per-thread 4 rows x TN cols. BM=64, BN=BNt, BK=16.
// LDS padded (+4 floats) so staging stores are conflict-free (2-way max).
// z dim = batch * NSK (split-K); partial written to C + z*sC.
template<int BNt, int TN, int NSK>
__global__ __launch_bounds__(256) void gemm_pf(
    const float* __restrict__ A, const float* __restrict__ B, float* __restrict__ Cc,
    int M, int N, int K, int lda, int ldb, int ldc,
    long sA, long sB, long sC)
{
    constexpr int BMt = 64, BK = 16;
    constexpr int NB = BNt / 16;
    int zz = blockIdx.z;
    int sk = zz % NSK, z = zz / NSK;
    int Kc = K / NSK;
    const float* Ab = A + (long)z * sA + (long)sk * Kc;
    const float* Bbp = B + (long)z * sB + (long)sk * Kc;
    float* Cb = Cc + (long)zz * sC;

    __shared__ float As[BK][BMt + 4];
    __shared__ float Bs[BK][BNt + 4];

    int t = threadIdx.x;
    int tx = t & 15, ty = t >> 4;
    int m0 = blockIdx.y * BMt, n0 = blockIdx.x * BNt;
    int ks = t & 15;        // staging k within tile
    int rs = t >> 4;        // staging row base

    float acc[4][TN];
#pragma unroll
    for (int i = 0; i < 4; ++i)
#pragma unroll
        for (int j = 0; j < TN; ++j) acc[i][j] = 0.f;

    float pa[4], pb[NB];
#pragma unroll
    for (int i = 0; i < 4; ++i) {
        int m = m0 + rs + 16 * i;
        pa[i] = (m < M) ? Ab[(long)m * lda + ks] : 0.f;
    }
#pragma unroll
    for (int i = 0; i < NB; ++i) {
        int n = n0 + rs + 16 * i;
        pb[i] = (n < N) ? Bbp[(long)n * ldb + ks] : 0.f;
    }

    int niter = Kc / BK;
    for (int it = 0; it < niter; ++it) {
#pragma unroll
        for (int i = 0; i < 4; ++i) As[ks][rs + 16 * i] = pa[i];
#pragma unroll
        for (int i = 0; i < NB; ++i) Bs[ks][rs + 16 * i] = pb[i];
        __syncthreads();
        if (it + 1 < niter) {
            int kof = (it + 1) * BK + ks;
#pragma unroll
            for (int i = 0; i < 4; ++i) {
                int m = m0 + rs + 16 * i;
                pa[i] = (m < M) ? Ab[(long)m * lda + kof] : 0.f;
            }
#pragma unroll
            for (int i = 0; i < NB; ++i) {
                int n = n0 + rs + 16 * i;
                pb[i] = (n < N) ? Bbp[(long)n * ldb + kof] : 0.f;
            }
        }
#pragma unroll
        for (int kk = 0; kk < BK; ++kk) {
            float a[4], b[TN];
#pragma unroll
            for (int i = 0; i < 4; ++i) a[i] = As[kk][ty * 4 + i];
#pragma unroll
            for (int j = 0; j < TN; ++j) b[j] = Bs[kk][tx * TN + j];
#pragma unroll
            for (int i = 0; i < 4; ++i)
#pragma unroll
                for (int j = 0; j < TN; ++j)
                    acc[i][j] += a[i] * b[j];
        }
        __syncthreads();
    }
#pragma unroll
    for (int i = 0; i < 4; ++i) {
        int m = m0 + ty * 4 + i;
        if (m >= M) continue;
#pragma unroll
        for (int j = 0; j < TN; ++j) {
            int n = n0 + tx * TN + j;
            if (n < N) Cb[(long)m * ldc + n] = acc[i][j];
        }
    }
}

// sum split-K partials: out[z][m][n] = sum_sk part[z*nsk+sk][m][n]
__global__ __launch_bounds__(256) void reduce_sk(
    const float* __restrict__ part, float* __restrict__ out,
    int M, int Nv, int ldp, int ldo, int nsk, long sSlice, long sOutZ, int nz)
{
    long idx = (long)blockIdx.x * 256 + threadIdx.x;
    long tot = (long)nz * M * Nv;
    if (idx >= tot) return;
    int n = (int)(idx % Nv);
    long r = idx / Nv;
    int m = (int)(r % M);
    int z = (int)(r / M);
    float s = 0.f;
    for (int sk = 0; sk < nsk; ++sk)
        s += part[(long)(z * nsk + sk) * sSlice + (long)m * ldp + n];
    out[(long)z * sOutZ + (long)m * ldo + n] = s;
}

// ---------------- prep: transpose A_log (pre-negated exp) and dt_w for coalesced scan loads ----------------
__global__ __launch_bounds__(256) void prep_kernel(
    const float* __restrict__ A_log, const float* __restrict__ dt_w,
    float* __restrict__ an_t, float* __restrict__ dtw_t)
{
    int t = blockIdx.x * 256 + threadIdx.x;   // over Kk*DIN
    if (t >= Kk * DINn) return;
    int d = t % DINn, k = t / DINn;
#pragma unroll
    for (int n = 0; n < DSs; ++n)
        an_t[((long)(k * DSs + n)) * DINn + d] = -__expf(A_log[((long)(k * DINn + d)) * DSs + n]);
#pragma unroll
    for (int r = 0; r < DTRr; ++r)
        dtw_t[((long)(k * DTRr + r)) * DINn + d] = dt_w[((long)(k * DINn + d)) * DTRr + r];
}

// ---------------- depthwise causal conv (k=4) + SiLU, with scan gather ----------------
__global__ __launch_bounds__(256) void conv_kernel(
    const float* __restrict__ xz, const float* __restrict__ conv_w,
    const float* __restrict__ conv_b, float* __restrict__ conv)
{
    int l = blockIdx.x;
    int kb = blockIdx.y;       // k*2 + b
    int k = kb >> 1, b = kb & 1;
    int p[4];
#pragma unroll
    for (int j = 0; j < 4; ++j) {
        int lp = l - 3 + j;
        p[j] = (lp >= 0) ? spos(k, lp) : -1;
    }
    for (int d = threadIdx.x; d < DINn; d += 256) {
        float acc = conv_b[k * DINn + d];
        const float* w = conv_w + (long)(k * DINn + d) * 4;
#pragma unroll
        for (int j = 0; j < 4; ++j) {
            if (p[j] >= 0)
                acc += w[j] * xz[((long)b * Ll + p[j]) * (2 * DINn) + d];
        }
        acc = acc / (1.f + __expf(-acc));   // SiLU
        conv[((long)kb * Ll + l) * DINn + d] = acc;
    }
}

// ---------------- chunked selective scan, pass 1 (delta fused in) ----------------
// thread = (kb, chunk c, d); d fastest across lanes; 16 states in registers.
// chunkA/chunkB layout: [kb][c][n][d]
__global__ __launch_bounds__(256) void scan1_kernel(
    const float* __restrict__ conv, const float* __restrict__ xdbl,
    const float* __restrict__ an_t, const float* __restrict__ dtw_t,
    const float* __restrict__ dt_b,
    float* __restrict__ chunkA, float* __restrict__ chunkB)
{
    int d = blockIdx.x * 256 + threadIdx.x;
    int c = blockIdx.y;
    int kb = blockIdx.z;
    int k = kb >> 1;

    __shared__ float xrow[CH][Ee];   // full x_dbl rows: dt(24) | B(16) | C(16)
    const float* xd = xdbl + ((long)kb * Ll + c * CH) * Ee;
    for (int u = threadIdx.x; u < CH * Ee; u += 256) xrow[u / Ee][u % Ee] = xd[u];
    __syncthreads();

    float dtw[DTRr];
#pragma unroll
    for (int r = 0; r < DTRr; ++r) dtw[r] = dtw_t[((long)(k * DTRr + r)) * DINn + d];
    float dtb = dt_b[k * DINn + d];
    float An[DSs], h[DSs];
#pragma unroll
    for (int n = 0; n < DSs; ++n) {
        An[n] = an_t[((long)(k * DSs + n)) * DINn + d];
        h[n] = 0.f;
    }
    const float* cl = conv + ((long)kb * Ll + c * CH) * DINn + d;
    float sumde = 0.f;
    for (int i = 0; i < CH; ++i) {
        float xlin = dtb;
#pragma unroll
        for (int r = 0; r < DTRr; ++r) xlin += dtw[r] * xrow[i][r];
        float de = softplusf(xlin);
        float cv = cl[(long)i * DINn];
        sumde += de;
        float dexc = de * cv;
#pragma unroll
        for (int n = 0; n < DSs; ++n)
            h[n] = __expf(de * An[n]) * h[n] + dexc * xrow[i][DTRr + n];
    }
    long o = (long)(kb * NC + c) * DSs * DINn + d;
#pragma unroll
    for (int n = 0; n < DSs; ++n) {
        chunkA[o + (long)n * DINn] = __expf(An[n] * sumde);
        chunkB[o + (long)n * DINn] = h[n];
    }
}

// ---------------- pass 1.5: serial combine of chunk states ----------------
__global__ __launch_bounds__(256) void scanfix_kernel(
    const float* __restrict__ chunkA, const float* __restrict__ chunkB,
    float* __restrict__ hin)
{
    int u = blockIdx.x * 256 + threadIdx.x;   // 0..98303
    int d = u % DINn;
    int rest = u / DINn;                      // kb*16 + n
    int n = rest & 15;
    int kb = rest >> 4;
    float h = 0.f;
#pragma unroll
    for (int c = 0; c < NC; ++c) {
        long idx = ((long)(kb * NC + c) * DSs + n) * DINn + d;
        hin[idx] = h;
        h = chunkA[idx] * h + chunkB[idx];
    }
}

// ---------------- pass 2: local scan from hin, C-reduce, gate, scatter (delta fused) ----------------
__global__ __launch_bounds__(256) void scan2_kernel(
    const float* __restrict__ conv, const float* __restrict__ xdbl,
    const float* __restrict__ an_t, const float* __restrict__ dtw_t,
    const float* __restrict__ dt_b, const float* __restrict__ Dp,
    const float* __restrict__ xz, const float* __restrict__ hin,
    float* __restrict__ outy)
{
    int d = blockIdx.x * 256 + threadIdx.x;
    int c = blockIdx.y;
    int kb = blockIdx.z;
    int k = kb >> 1, b = kb & 1;

    __shared__ float xrow[CH][Ee];
    const float* xd = xdbl + ((long)kb * Ll + c * CH) * Ee;
    for (int u = threadIdx.x; u < CH * Ee; u += 256) xrow[u / Ee][u % Ee] = xd[u];
    __syncthreads();

    float dtw[DTRr];
#pragma unroll
    for (int r = 0; r < DTRr; ++r) dtw[r] = dtw_t[((long)(k * DTRr + r)) * DINn + d];
    float dtb = dt_b[k * DINn + d];
    float An[DSs], h[DSs];
    long o = (long)(kb * NC + c) * DSs * DINn + d;
#pragma unroll
    for (int n = 0; n < DSs; ++n) {
        An[n] = an_t[((long)(k * DSs + n)) * DINn + d];
        h[n] = hin[o + (long)n * DINn];
    }
    float Dv = Dp[k * DINn + d];
    const float* cl = conv + ((long)kb * Ll + c * CH) * DINn + d;
    for (int i = 0; i < CH; ++i) {
        float xlin = dtb;
#pragma unroll
        for (int r = 0; r < DTRr; ++r) xlin += dtw[r] * xrow[i][r];
        float de = softplusf(xlin);
        float cv = cl[(long)i * DINn];
        float dexc = de * cv;
        float y = 0.f;
#pragma unroll
        for (int n = 0; n < DSs; ++n) {
            h[n] = __expf(de * An[n]) * h[n] + dexc * xrow[i][DTRr + n];
            y += h[n] * xrow[i][DTRr + DSs + n];
        }
        y += Dv * cv;
        int l = c * CH + i;
        int p = spos(k, l);
        float zv = xz[((long)b * Ll + p) * (2 * DINn) + DINn + d];
        y *= zv / (1.f + __expf(-zv));
        outy[((long)kb * Ll + p) * DINn + d] = y;
    }
}

// ---------------- LayerNorm stats per (kb, l) ----------------
__global__ __launch_bounds__(256) void ln_stats_kernel(
    const float* __restrict__ outy, float* __restrict__ mu, float* __restrict__ rstd)
{
    int l = blockIdx.x, kb = blockIdx.y;
    const float* row = outy + ((long)kb * Ll + l) * DINn;
    float s = 0.f, ss = 0.f;
    for (int d = threadIdx.x; d < DINn; d += 256) {
        float v = row[d];
        s += v; ss += v * v;
    }
#pragma unroll
    for (int o = 32; o > 0; o >>= 1) {
        s += __shfl_down(s, o);
        ss += __shfl_down(ss, o);
    }
    __shared__ float sh[8];
    int wid = threadIdx.x >> 6;
    if ((threadIdx.x & 63) == 0) { sh[wid] = s; sh[wid + 4] = ss; }
    __syncthreads();
    if (threadIdx.x == 0) {
        s = sh[0] + sh[1] + sh[2] + sh[3];
        ss = sh[4] + sh[5] + sh[6] + sh[7];
        float m = s / DINn;
        float var = ss / DINn - m * m;
        mu[(long)kb * Ll + l] = m;
        rstd[(long)kb * Ll + l] = rsqrtf(var + 1e-5f);
    }
}

// ---------------- partial g: gpart[kb][c][d] over l-chunks ----------------
__global__ __launch_bounds__(768) void gpart_kernel(
    const float* __restrict__ outy, const float* __restrict__ mu,
    const float* __restrict__ rstd, float* __restrict__ gpart)
{
    int kb = blockIdx.x;
    int c = blockIdx.y;
    int d = threadIdx.x;
    float acc = 0.f;
    int l0 = c * CH;
    for (int i = 0; i < CH; ++i) {
        int l = l0 + i;
        float v = outy[((long)kb * Ll + l) * DINn + d];
        acc += (v - mu[(long)kb * Ll + l]) * rstd[(long)kb * Ll + l];
    }
    gpart[((long)kb * NC + c) * DINn + d] = acc;
}

// ---------------- attn[kb][d] = sigmoid(cs(gelu(gr(g)))) ----------------
__global__ __launch_bounds__(256) void attn_kernel(
    const float* __restrict__ gpart, const float* __restrict__ ln_g,
    const float* __restrict__ ln_b, const float* __restrict__ gr_w,
    const float* __restrict__ gr_b, const float* __restrict__ cs_w,
    const float* __restrict__ cs_b, float* __restrict__ attn)
{
    __shared__ float gs[DINn];
    __shared__ float hs[96];
    int kb = blockIdx.x;
    int t = threadIdx.x;
    for (int d = t; d < DINn; d += 256) {
        float s = 0.f;
#pragma unroll
        for (int c = 0; c < NC; ++c)
            s += gpart[((long)kb * NC + c) * DINn + d];
        gs[d] = ln_g[d] * (s / (float)Ll) + ln_b[d];
    }
    __syncthreads();
    if (t < 96) {
        float a = gr_b[t];
        const float* wrow = gr_w + (long)t * DINn;
        for (int d = 0; d < DINn; ++d) a += wrow[d] * gs[d];
        hs[t] = 0.5f * a * (1.f + erff(a * 0.70710678118654752f));  // exact gelu
    }
    __syncthreads();
    for (int d = t; d < DINn; d += 256) {
        float a = cs_b[d];
        const float* wrow = cs_w + (long)d * 96;
        for (int e = 0; e < 96; ++e) a += wrow[e] * hs[e];
        attn[kb * DINn + d] = 1.f / (1.f + __expf(-a));
    }
}

// ---------------- weighted sum over directions ----------------
__global__ __launch_bounds__(256) void wsum_kernel(
    const float* __restrict__ outy, const float* __restrict__ attn,
    float* __restrict__ sbuf)
{
    long idx = (long)blockIdx.x * 256 + threadIdx.x;   // over B*L*DIN
    if (idx >= (long)Bb * Ll * DINn) return;
    int d = idx % DINn;
    long bl = idx / DINn;          // b*L + p
    int b = (int)(bl / Ll);
    float acc = 0.f;
#pragma unroll
    for (int k = 0; k < Kk; ++k) {
        int kb = k * 2 + b;
        acc += outy[((long)kb * Ll + (bl % Ll)) * DINn + d] * attn[kb * DINn + d];
    }
    sbuf[idx] = acc;
}

extern "C" void kernel_launch(void* const* d_in, const int* in_sizes, int n_in,
                              void* d_out, int out_size, void* d_ws, size_t ws_size,
                              hipStream_t stream) {
    const float* x         = (const float*)d_in[0];
    const float* in_proj_w = (const float*)d_in[1];
    const float* conv_w    = (const float*)d_in[2];
    const float* conv_b    = (const float*)d_in[3];
    const float* x_proj_w  = (const float*)d_in[4];
    const float* dt_w      = (const float*)d_in[5];
    const float* dt_b      = (const float*)d_in[6];
    const float* A_log     = (const float*)d_in[7];
    const float* Dp        = (const float*)d_in[8];
    const float* ln_g      = (const float*)d_in[9];
    const float* ln_b      = (const float*)d_in[10];
    const float* gr_w      = (const float*)d_in[11];
    const float* gr_b      = (const float*)d_in[12];
    const float* cs_w      = (const float*)d_in[13];
    const float* cs_b      = (const float*)d_in[14];
    const float* out_proj_w= (const float*)d_in[15];
    float* out = (float*)d_out;

    float* ws    = (float*)d_ws;
    float* xz    = ws;                                    // 2*784*1536
    float* conv  = xz   + (long)Bb * Ll * 2 * DINn;       // 8*784*768
    float* xdbl  = conv + (long)Kk * BL * DINn;           // 4*1568*56
    float* outy  = xdbl + (long)Kk * BL * Ee;             // 8*784*768
    float* mu    = outy + (long)Kk * BL * DINn;           // 8*784
    float* rstd  = mu   + Kk * BL;
    float* gpart = rstd + Kk * BL;                        // 8*NC*768
    float* attn  = gpart + (long)Kk * Bb * NC * DINn;     // 8*768
    float* an_t  = attn + 2 * Kk * DINn;                  // 4*16*768
    float* dtw_t = an_t + (long)Kk * DSs * DINn;          // 4*24*768
    float* sbuf  = dtw_t + (long)Kk * DTRr * DINn;        // 2*784*768
    float* arena = sbuf + (long)Bb * Ll * DINn;           // shared scratch
    // arena overlays (sequentially live):
    float* part3  = arena;                                // 16 * 1568*64
    float* chunkA = arena;                                // 8*NC*16*768
    float* chunkB = chunkA + (long)Kk * Bb * NC * DSs * DINn;
    float* hin    = chunkB + (long)Kk * Bb * NC * DSs * DINn;
    float* part10 = arena;                                // 2 * 1568*384

    // 0) prep transposed An / dt_w tables
    prep_kernel<<<dim3((Kk * DINn + 255) / 256), 256, 0, stream>>>(A_log, dt_w, an_t, dtw_t);

    // 1) xz = x @ in_proj_w.T   (M=1568, N=1536, K=384)
    gemm_pf<128, 8, 1><<<dim3(1536 / 128, (BL + 63) / 64, 1), 256, 0, stream>>>(
        x, in_proj_w, xz, BL, 2 * DINn, DMm, DMm, DMm, 2 * DINn, 0, 0, 0);

    // 2) depthwise conv + SiLU (gathered per direction)
    conv_kernel<<<dim3(Ll, Kk * Bb), 256, 0, stream>>>(xz, conv_w, conv_b, conv);

    // 3) x_dbl = conv @ x_proj_w.T  per k  (M=1568, N=56, K=768), split-K=4
    gemm_pf<64, 4, 4><<<dim3(1, (BL + 63) / 64, Kk * 4), 256, 0, stream>>>(
        conv, x_proj_w, part3, BL, Ee, DINn, DINn, DINn, 64,
        (long)BL * DINn, (long)Ee * DINn, (long)BL * 64);
    reduce_sk<<<dim3((Kk * BL * Ee + 255) / 256), 256, 0, stream>>>(
        part3, xdbl, BL, Ee, 64, Ee, 4, (long)BL * 64, (long)BL * Ee, Kk);

    // 4) chunked selective scan (delta fused; d fastest across lanes)
    scan1_kernel<<<dim3(DINn / 256, NC, Kk * Bb), 256, 0, stream>>>(
        conv, xdbl, an_t, dtw_t, dt_b, chunkA, chunkB);
    scanfix_kernel<<<dim3((Kk * Bb * DSs * DINn) / 256), 256, 0, stream>>>(
        chunkA, chunkB, hin);
    scan2_kernel<<<dim3(DINn / 256, NC, Kk * Bb), 256, 0, stream>>>(
        conv, xdbl, an_t, dtw_t, dt_b, Dp, xz, hin, outy);

    // 5) LN stats per (kb,l)
    ln_stats_kernel<<<dim3(Ll, Kk * Bb), 256, 0, stream>>>(outy, mu, rstd);

    // 6) partial g per (kb, l-chunk)
    gpart_kernel<<<dim3(Kk * Bb, NC), 768, 0, stream>>>(outy, mu, rstd, gpart);

    // 7) attention vector per kb
    attn_kernel<<<dim3(Kk * Bb), 256, 0, stream>>>(
        gpart, ln_g, ln_b, gr_w, gr_b, cs_w, cs_b, attn);

    // 8) weighted direction sum
    wsum_kernel<<<dim3((Bb * Ll * DINn + 255) / 256), 256, 0, stream>>>(outy, attn, sbuf);

    // 9) out = sbuf @ out_proj_w.T  (M=1568, N=384, K=768), split-K=2
    gemm_pf<64, 4, 2><<<dim3(DMm / 64, (BL + 63) / 64, 2), 256, 0, stream>>>(
        sbuf, out_proj_w, part10, BL, DMm, DINn, DINn, DINn, DMm,
        0, 0, (long)BL * DMm);
    reduce_sk<<<dim3((BL * DMm + 255) / 256), 256, 0, stream>>>(
        part10, out, BL, DMm, DMm, DMm, 2, (long)BL * DMm, 0, 1);
}